// Round 16
// baseline (605.693 us; speedup 1.0000x reference)
//
#include <hip/hip_runtime.h>

#define T_LEN 1024
#define HID   32
#define LDIM  16
#define BATCH 512
#define NB    4              // batch elems per block (B columns duplicated x4)
#define NT    192            // 3 waves: one per layer
#define NSLOT 8              // cross-layer ring depth
#define LOG2E 1.44269504f

typedef _Float16 half8  __attribute__((ext_vector_type(8)));
typedef _Float16 half2v __attribute__((ext_vector_type(2)));
typedef float    f32x4  __attribute__((ext_vector_type(4)));
typedef unsigned u32;
typedef unsigned u32x4  __attribute__((ext_vector_type(4)));

#if defined(__has_builtin)
#if __has_builtin(__builtin_amdgcn_rcpf)
#define FAST_RCP(x) __builtin_amdgcn_rcpf(x)
#endif
#if __has_builtin(__builtin_amdgcn_exp2f)
#define FAST_EXP2(x) __builtin_amdgcn_exp2f(x)
#endif
#if __has_builtin(__builtin_amdgcn_cvt_pkrtz)
#define PKRTZ(a, b) __builtin_bit_cast(u32, __builtin_amdgcn_cvt_pkrtz((a), (b)))
#endif
#endif
#ifndef FAST_RCP
#define FAST_RCP(x) (1.0f / (x))
#endif
#ifndef FAST_EXP2
#define FAST_EXP2(x) __expf(0.69314718f * (x))
#endif
#ifndef PKRTZ
static __device__ __forceinline__ u32 pkrtz_fallback(float a, float b) {
    half2v v; v[0] = (_Float16)a; v[1] = (_Float16)b;
    return __builtin_bit_cast(u32, v);
}
#define PKRTZ(a, b) pkrtz_fallback((a), (b))
#endif

#define MFMA(a, b, c) __builtin_amdgcn_mfma_f32_16x16x32_f16((a), (b), (c), 0, 0, 0)

// BitMode ds_swizzle within 32-lane groups: dst lane reads lane^xor
template <int OFF>
__device__ __forceinline__ u32 swzu(u32 v) {
    return (u32)__builtin_amdgcn_ds_swizzle((int)v, OFF);
}

__device__ __forceinline__ void waitc(const u32* p, u32 need) {
    while (__hip_atomic_load(p, __ATOMIC_ACQUIRE, __HIP_MEMORY_SCOPE_WORKGROUP) < need)
        __builtin_amdgcn_s_sleep(2);
}

// static-index select of v[hi], hi in 0..3 (rule #20: no dynamic vector indexing)
__device__ __forceinline__ float sel4(f32x4 v, int hi) {
    const float a = (hi & 1) ? v[1] : v[0];
    const float b = (hi & 1) ? v[3] : v[2];
    return (hi & 2) ? b : a;
}

__global__ __launch_bounds__(NT, 1)
void lstm_encoder_kernel(const float* __restrict__ x,
                         const float* __restrict__ Wih0, const float* __restrict__ Whh0,
                         const float* __restrict__ bih0, const float* __restrict__ bhh0,
                         const float* __restrict__ Wih1, const float* __restrict__ Whh1,
                         const float* __restrict__ bih1, const float* __restrict__ bhh1,
                         const float* __restrict__ Wih2, const float* __restrict__ Whh2,
                         const float* __restrict__ bih2, const float* __restrict__ bhh2,
                         const float* __restrict__ Wm,  const float* __restrict__ bm,
                         const float* __restrict__ Wlv, const float* __restrict__ blv,
                         float* __restrict__ out)
{
    const int b0   = blockIdx.x * NB;
    const int tid  = threadIdx.x;
    const int lane = tid & 63;
    const int l    = tid >> 6;        // wave = layer 0..2
    const int n    = lane & 15;       // B/D column; batch = n&3 (cols duplicated x4)
    const int kc   = lane >> 4;       // k-group / D row-quad
    const int nb   = n & 3;           // batch row
    const int hi   = n >> 2;          // duplicate index 0..3: owns units 8kc+hi, 8kc+4+hi

    __shared__ u32 xs[T_LEN * NB];                    // 16 KB packed f16 x pairs [t][nb]
    __shared__ __align__(16) u32x4 ring[2][NSLOT][4][NB];  // 4 KB cross-layer h
    __shared__ u32 cnt[48];                           // per-layer counters, 64B apart
    __shared__ float cbuf[NB * HID];

    // ---- stage all x into LDS as f16 pairs (coalesced) ----
    for (int i = tid; i < NB * T_LEN; i += NT) {
        const int nn = i >> 10, t = i & (T_LEN - 1);
        const float2 v = *(const float2*)(x + ((size_t)(b0 + nn) * T_LEN + t) * 2);
        half2v p; p[0] = (_Float16)v.x; p[1] = (_Float16)v.y;
        xs[t * NB + nn] = __builtin_bit_cast(u32, p);
    }
    if (tid < 48) cnt[tid] = 0u;

    // ---- A fragments + bias, exp2-prescaled; 8 tiles tau = role*2 + half ----
    // A row m (= n) -> gate row R = role*32 + 8*(m>>2) + 4*half + (m&3)   [r10-verified]
    // D row (4kc+r) -> unit 8kc + 4*half + r  => lane owns units 8kc..8kc+7 across tiles.
    // CANONICAL k order for BOTH operand paths (column-independent; fixes r15):
    //   element 2j+p <-> k = 8kc + 4p + j
    const float* Wih = (l == 0) ? Wih0 : (l == 1) ? Wih1 : Wih2;
    const float* Whh = (l == 0) ? Whh0 : (l == 1) ? Whh1 : Whh2;
    const float* bih = (l == 0) ? bih0 : (l == 1) ? bih1 : bih2;
    const float* bhh = (l == 0) ? bhh0 : (l == 1) ? bhh1 : bhh2;

    half8 aself[8], aprev[8];
    f32x4 biasC[8];
#pragma unroll
    for (int tau = 0; tau < 8; ++tau) {
        const int   role = tau >> 1, half = tau & 1;
        const float sc   = (role == 2) ? (2.0f * LOG2E) : LOG2E;
        const int   R    = role * 32 + 8 * (n >> 2) + 4 * half + (n & 3);
#pragma unroll
        for (int j = 0; j < 4; ++j) {
#pragma unroll
            for (int p = 0; p < 2; ++p) {
                const int kidx = 8 * kc + 4 * p + j;        // canonical order
                aself[tau][2 * j + p] = (_Float16)(Whh[R * HID + kidx] * sc);
                aprev[tau][2 * j + p] = (l == 0)
                    ? (_Float16)((kc == 0 && (2 * j + p) < 2) ? Wih[R * 2 + 2 * j + p] * sc : 0.0f)
                    : (_Float16)(Wih[R * HID + kidx] * sc);
            }
        }
#pragma unroll
        for (int r = 0; r < 4; ++r) {
            const int   RD  = role * 32 + 8 * kc + 4 * half + r;
            const float scD = (role == 2) ? (2.0f * LOG2E) : LOG2E;
            biasC[tau][r] = (bih[RD] + bhh[RD]) * scD;
        }
    }

    u32* cs = &cnt[l * 16];
    u32* cp = &cnt[((l > 0) ? (l - 1) : 0) * 16];
    u32* cn = &cnt[((l < 2) ? (l + 1) : 0) * 16];

    u32x4 hB = {0u, 0u, 0u, 0u};   // own-layer B-frag (h(t-1)), canonical, lane-local
    float cc0 = 0.0f, cc1 = 0.0f;  // cells: units 8kc+hi, 8kc+4+hi (batch nb)

    __syncthreads();

    for (int t = 0; t < T_LEN; ++t) {
        const int s = t & (NSLOT - 1);
        if (l > 0)                 waitc(cp, (u32)(t + 1));           // h_{l-1}(t) ready
        if (l < 2 && t >= NSLOT)   waitc(cn, (u32)(t - (NSLOT - 1))); // ring backpressure

        u32x4 bf0;
        if (l == 0) {
            bf0[0] = (kc == 0) ? xs[t * NB + nb] : 0u;
            bf0[1] = 0u; bf0[2] = 0u; bf0[3] = 0u;
        } else {
            bf0 = ring[l - 1][s][kc][nb];
        }

        __builtin_amdgcn_s_setprio(1);

        f32x4 acc[8];
#pragma unroll
        for (int tau = 0; tau < 8; ++tau)
            acc[tau] = MFMA(aprev[tau], __builtin_bit_cast(half8, bf0), biasC[tau]);
#pragma unroll
        for (int tau = 0; tau < 8; ++tau)
            acc[tau] = MFMA(aself[tau], __builtin_bit_cast(half8, hB), acc[tau]);

        // extract this lane's 2 cells (unit 8kc+hi: half0; unit 8kc+4+hi: half1)
        const float ai0 = sel4(acc[0], hi), ai1 = sel4(acc[1], hi);
        const float af0 = sel4(acc[2], hi), af1 = sel4(acc[3], hi);
        const float ag0 = sel4(acc[4], hi), ag1 = sel4(acc[5], hi);
        const float ao0 = sel4(acc[6], hi), ao1 = sel4(acc[7], hi);

        float h0, h1;
        {
            const float ei = FAST_EXP2(-ai0), ef = FAST_EXP2(-af0);
            const float eg = FAST_EXP2(-ag0), eo = FAST_EXP2(-ao0);
            const float p1  = (1.0f + ei) * (1.0f + eg);
            const float den = p1 * (1.0f + ef);
            const float tmn = (1.0f - eg) * (1.0f + ef);
            float c_ = fmaf(cc0, p1, tmn) * FAST_RCP(den);
            c_ = fminf(fmaxf(c_, -20.0f), 20.0f);
            cc0 = c_;
            const float ec = FAST_EXP2(-2.0f * LOG2E * c_);
            h0 = (1.0f - ec) * FAST_RCP((1.0f + eo) * (1.0f + ec));
        }
        {
            const float ei = FAST_EXP2(-ai1), ef = FAST_EXP2(-af1);
            const float eg = FAST_EXP2(-ag1), eo = FAST_EXP2(-ao1);
            const float p1  = (1.0f + ei) * (1.0f + eg);
            const float den = p1 * (1.0f + ef);
            const float tmn = (1.0f - eg) * (1.0f + ef);
            float c_ = fmaf(cc1, p1, tmn) * FAST_RCP(den);
            c_ = fminf(fmaxf(c_, -20.0f), 20.0f);
            cc1 = c_;
            const float ec = FAST_EXP2(-2.0f * LOG2E * c_);
            h1 = (1.0f - ec) * FAST_RCP((1.0f + eo) * (1.0f + ec));
        }

        // exchange within the duplicate quad (lane^4/^8/^12), then CANONICALIZE:
        // candidate x holds pk of lane hi^x; canonical dword j needs lane hi'=j -> x = j^hi
        const u32 q0 = PKRTZ(h0, h1);
        const u32 q1 = swzu<0x101F>(q0);   // xor-4  -> lane hi^1
        const u32 q2 = swzu<0x201F>(q0);   // xor-8  -> lane hi^2
        const u32 q3 = swzu<0x301F>(q0);   // xor-12 -> lane hi^3
#define SELX(j) ((hi == (j)) ? q0 : (hi == ((j) ^ 1)) ? q1 : (hi == ((j) ^ 2)) ? q2 : q3)
        hB[0] = SELX(0); hB[1] = SELX(1); hB[2] = SELX(2); hB[3] = SELX(3);
#undef SELX

        if (l < 2 && hi == 0) ring[l][s][kc][nb] = hB;    // canonical order

        __builtin_amdgcn_s_setprio(0);

        if (lane == 0)
            __hip_atomic_fetch_add(cs, 1u, __ATOMIC_RELEASE, __HIP_MEMORY_SCOPE_WORKGROUP);
    }

    // ---- final c3 of layer 2 -> LDS ----
    if (l == 2) {
        cbuf[nb * HID + 8 * kc + hi]     = cc0;
        cbuf[nb * HID + 8 * kc + 4 + hi] = cc1;
    }
    __syncthreads();

    // ---- projection: mean / log_var ----
    if (tid < NB * 2 * LDIM) {
        const int  nn = tid >> 5;
        const int  o  = tid & 31;
        const bool is_mean = (o < LDIM);
        const int  jo = o & (LDIM - 1);
        const float* W  = is_mean ? Wm : Wlv;
        float acc = is_mean ? bm[jo] : blv[jo];
#pragma unroll
        for (int k = 0; k < HID; ++k) acc = fmaf(W[jo * HID + k], cbuf[nn * HID + k], acc);
        out[(is_mean ? 0 : (size_t)BATCH * LDIM) + (size_t)(b0 + nn) * LDIM + jo] = acc;
    }
}

extern "C" void kernel_launch(void* const* d_in, const int* in_sizes, int n_in,
                              void* d_out, int out_size, void* d_ws, size_t ws_size,
                              hipStream_t stream) {
    const float* x    = (const float*)d_in[0];
    const float* Wih0 = (const float*)d_in[1];
    const float* Whh0 = (const float*)d_in[2];
    const float* bih0 = (const float*)d_in[3];
    const float* bhh0 = (const float*)d_in[4];
    const float* Wih1 = (const float*)d_in[5];
    const float* Whh1 = (const float*)d_in[6];
    const float* bih1 = (const float*)d_in[7];
    const float* bhh1 = (const float*)d_in[8];
    const float* Wih2 = (const float*)d_in[9];
    const float* Whh2 = (const float*)d_in[10];
    const float* bih2 = (const float*)d_in[11];
    const float* bhh2 = (const float*)d_in[12];
    const float* Wm   = (const float*)d_in[13];
    const float* bm   = (const float*)d_in[14];
    const float* Wlv  = (const float*)d_in[15];
    const float* blv  = (const float*)d_in[16];
    float* out = (float*)d_out;

    lstm_encoder_kernel<<<dim3(BATCH / NB), dim3(NT), 0, stream>>>(
        x, Wih0, Whh0, bih0, bhh0, Wih1, Whh1, bih1, bhh1,
        Wih2, Whh2, bih2, bhh2, Wm, bm, Wlv, blv, out);
}

// Round 17
// 481.958 us; speedup vs baseline: 1.2567x; 1.2567x over previous
//
#include <hip/hip_runtime.h>

#define T_LEN 1024
#define HID   32
#define LDIM  16
#define BATCH 512
#define NB    4              // batch elems per block (B cols duplicated x4)
#define NT    384            // 6 waves: 3 layers x 2 unit-halves
#define NSLOT 8              // ring depth
#define LOG2E 1.44269504f

typedef _Float16 half8  __attribute__((ext_vector_type(8)));
typedef _Float16 half2v __attribute__((ext_vector_type(2)));
typedef float    f32x4  __attribute__((ext_vector_type(4)));
typedef unsigned u32;
typedef unsigned u32x4  __attribute__((ext_vector_type(4)));

#if defined(__has_builtin)
#if __has_builtin(__builtin_amdgcn_rcpf)
#define FAST_RCP(x) __builtin_amdgcn_rcpf(x)
#endif
#if __has_builtin(__builtin_amdgcn_exp2f)
#define FAST_EXP2(x) __builtin_amdgcn_exp2f(x)
#endif
#endif
#ifndef FAST_RCP
#define FAST_RCP(x) (1.0f / (x))
#endif
#ifndef FAST_EXP2
#define FAST_EXP2(x) __expf(0.69314718f * (x))
#endif

#define MFMA(a, b, c) __builtin_amdgcn_mfma_f32_16x16x32_f16((a), (b), (c), 0, 0, 0)

__device__ __forceinline__ void waitc(const u32* p, u32 need) {
    while (__hip_atomic_load(p, __ATOMIC_ACQUIRE, __HIP_MEMORY_SCOPE_WORKGROUP) < need)
        __builtin_amdgcn_s_sleep(2);
}

__global__ __launch_bounds__(NT, 1)
void lstm_encoder_kernel(const float* __restrict__ x,
                         const float* __restrict__ Wih0, const float* __restrict__ Whh0,
                         const float* __restrict__ bih0, const float* __restrict__ bhh0,
                         const float* __restrict__ Wih1, const float* __restrict__ Whh1,
                         const float* __restrict__ bih1, const float* __restrict__ bhh1,
                         const float* __restrict__ Wih2, const float* __restrict__ Whh2,
                         const float* __restrict__ bih2, const float* __restrict__ bhh2,
                         const float* __restrict__ Wm,  const float* __restrict__ bm,
                         const float* __restrict__ Wlv, const float* __restrict__ blv,
                         float* __restrict__ out)
{
    const int b0   = blockIdx.x * NB;
    const int tid  = threadIdx.x;
    const int lane = tid & 63;
    const int wave = tid >> 6;        // 0..5
    // map heavy layers (1,2) onto the first four waves (likely 2-wave SIMDs under
    // round-robin placement); light layer 0 (no prev-MFMA) takes the rest.
    const int l    = (wave < 2) ? 1 : (wave < 4) ? 0 : 2;
    const int v    = wave & 1;        // unit half: units 16v..16v+15
    const int n    = lane & 15;       // B/D column; batch = n&3 (cols duplicated x4)
    const int kc   = lane >> 4;       // k-group / D row-quad
    const int nb   = n & 3;           // batch row
    const int hi   = n >> 2;          // tile select 0..3
    const int unit = 16 * v + 4 * hi + kc;   // this lane's owned unit

    __shared__ u32 xs[T_LEN * NB];                       // 16 KB packed f16 x [t][nb]
    __shared__ __align__(16) u32x4 ring[3][NSLOT][4][NB];  // 6 KB h ring, linear elem order
    __shared__ u32 cnt[48];                              // per-layer counters, 64B apart
    __shared__ float cbuf[NB * HID];

    // ---- stage all x into LDS as f16 pairs (coalesced) ----
    for (int i = tid; i < NB * T_LEN; i += NT) {
        const int nn = i >> 10, t = i & (T_LEN - 1);
        const float2 vv = *(const float2*)(x + ((size_t)(b0 + nn) * T_LEN + t) * 2);
        half2v p; p[0] = (_Float16)vv.x; p[1] = (_Float16)vv.y;
        xs[t * NB + nn] = __builtin_bit_cast(u32, p);
    }
    for (int i = tid; i < (int)(sizeof(ring) / 4); i += NT) ((u32*)ring)[i] = 0u;
    if (tid < 48) cnt[tid] = 0u;

    // ---- A fragments + bias, exp2-prescaled; 4 full-role tiles ----
    // A row m: role = m&3, uloc = m>>2 -> gate row R = (m&3)*32 + 16v + 4tau + (m>>2)
    // D reg r (row 4kc+r) -> gate r of unit 16v + 4tau + kc     [r14-verified mapping]
    // k order LINEAR: element e <-> k = 8kc + e                  [r14-verified]
    const float* Wih = (l == 0) ? Wih0 : (l == 1) ? Wih1 : Wih2;
    const float* Whh = (l == 0) ? Whh0 : (l == 1) ? Whh1 : Whh2;
    const float* bih = (l == 0) ? bih0 : (l == 1) ? bih1 : bih2;
    const float* bhh = (l == 0) ? bhh0 : (l == 1) ? bhh1 : bhh2;

    half8 aprev[4], aself[4];
    f32x4 biasC[4];
    float wx0v[4], wx1v[4];
#pragma unroll
    for (int tau = 0; tau < 4; ++tau) {
        const int   R  = (n & 3) * 32 + 16 * v + 4 * tau + (n >> 2);
        const float sc = ((n & 3) == 2) ? (2.0f * LOG2E) : LOG2E;   // g rows 2x
#pragma unroll
        for (int e = 0; e < 8; ++e) {
            const int kk = 8 * kc + e;
            aself[tau][e] = (_Float16)(Whh[R * HID + kk] * sc);
            aprev[tau][e] = (l > 0) ? (_Float16)(Wih[R * HID + kk] * sc) : (_Float16)0.0f;
        }
#pragma unroll
        for (int r = 0; r < 4; ++r) {
            const int   RD  = r * 32 + 16 * v + 4 * tau + kc;
            const float scD = (r == 2) ? (2.0f * LOG2E) : LOG2E;
            biasC[tau][r] = (bih[RD] + bhh[RD]) * scD;
        }
    }
#pragma unroll
    for (int r = 0; r < 4; ++r) {       // l==0: x weights for the lane's OWN cell
        const int   RD  = r * 32 + unit;
        const float scD = (r == 2) ? (2.0f * LOG2E) : LOG2E;
        wx0v[r] = (l == 0) ? Wih[RD * 2 + 0] * scD : 0.0f;
        wx1v[r] = (l == 0) ? Wih[RD * 2 + 1] * scD : 0.0f;
    }

    u32* cs = &cnt[l * 16];
    u32* cp = &cnt[((l > 0) ? (l - 1) : 0) * 16];
    u32* cn = &cnt[((l < 2) ? (l + 1) : 0) * 16];

    float cc = 0.0f;   // this lane's cell (unit, batch nb)

    __syncthreads();

    for (int tb = 0; tb < T_LEN; tb += NSLOT) {
#pragma unroll
        for (int s = 0; s < NSLOT; ++s) {
            const int t = tb + s;
            // sum-counter protocol: cs>=2t <=> both own waves finished t-1 (lockstep proof)
            if (t > 0)               waitc(cs, 2u * (u32)t);
            if (l > 0)               waitc(cp, 2u * (u32)(t + 1));          // h_{l-1}(t) ready
            if (l < 2 && t >= NSLOT) waitc(cn, 2u * (u32)(t - (NSLOT - 1))); // backpressure

            const u32x4 bf1 = ring[l][(s + NSLOT - 1) & (NSLOT - 1)][kc][nb];  // h_l(t-1)

            __builtin_amdgcn_s_setprio(1);
            f32x4 a0, a1, a2, a3;
            if (l == 0) {
                a0 = MFMA(aself[0], __builtin_bit_cast(half8, bf1), biasC[0]);
                a1 = MFMA(aself[1], __builtin_bit_cast(half8, bf1), biasC[1]);
                a2 = MFMA(aself[2], __builtin_bit_cast(half8, bf1), biasC[2]);
                a3 = MFMA(aself[3], __builtin_bit_cast(half8, bf1), biasC[3]);
            } else {
                const u32x4 bf0 = ring[l - 1][s][kc][nb];                      // h_{l-1}(t)
                a0 = MFMA(aprev[0], __builtin_bit_cast(half8, bf0), biasC[0]);
                a1 = MFMA(aprev[1], __builtin_bit_cast(half8, bf0), biasC[1]);
                a2 = MFMA(aprev[2], __builtin_bit_cast(half8, bf0), biasC[2]);
                a3 = MFMA(aprev[3], __builtin_bit_cast(half8, bf0), biasC[3]);
                a0 = MFMA(aself[0], __builtin_bit_cast(half8, bf1), a0);
                a1 = MFMA(aself[1], __builtin_bit_cast(half8, bf1), a1);
                a2 = MFMA(aself[2], __builtin_bit_cast(half8, bf1), a2);
                a3 = MFMA(aself[3], __builtin_bit_cast(half8, bf1), a3);
            }

            // extract own cell's 4 gates: tile hi, reg r (static indices, cndmask tree)
#define SELR(r) ((hi & 2) ? ((hi & 1) ? a3[r] : a2[r]) : ((hi & 1) ? a1[r] : a0[r]))
            float gi = SELR(0), gf = SELR(1), gg = SELR(2), go = SELR(3);
#undef SELR
            if (l == 0) {   // x contribution post-extraction (replaces 4 prev-MFMAs)
                const half2v xp = __builtin_bit_cast(half2v, xs[t * NB + nb]);
                const float x0 = (float)xp[0], x1 = (float)xp[1];
                gi = fmaf(wx1v[0], x1, fmaf(wx0v[0], x0, gi));
                gf = fmaf(wx1v[1], x1, fmaf(wx0v[1], x0, gf));
                gg = fmaf(wx1v[2], x1, fmaf(wx0v[2], x0, gg));
                go = fmaf(wx1v[3], x1, fmaf(wx0v[3], x0, go));
            }

            // CELL: 7 transcendentals (r11-verified math)
            const float ei  = FAST_EXP2(-gi);
            const float ef  = FAST_EXP2(-gf);
            const float eg  = FAST_EXP2(-gg);
            const float eo  = FAST_EXP2(-go);
            const float p1  = (1.0f + ei) * (1.0f + eg);
            const float den = p1 * (1.0f + ef);
            const float tmn = (1.0f - eg) * (1.0f + ef);
            float c_ = fmaf(cc, p1, tmn) * FAST_RCP(den);
            c_ = fminf(fmaxf(c_, -20.0f), 20.0f);
            cc = c_;
            const float ec = FAST_EXP2(-2.0f * LOG2E * c_);
            const float hv = (1.0f - ec) * FAST_RCP((1.0f + eo) * (1.0f + ec));  // o*tanh(c)

            // publish h(t): unit -> (kcB = unit>>3, element = unit&7), linear order
            *(_Float16*)((char*)&ring[l][s][unit >> 3][nb] + (unit & 7) * 2) = (_Float16)hv;
            __builtin_amdgcn_s_setprio(0);

            if (lane == 0)
                __hip_atomic_fetch_add(cs, 1u, __ATOMIC_RELEASE, __HIP_MEMORY_SCOPE_WORKGROUP);
        }
    }

    // ---- final c3 of layer 2 -> LDS ----
    if (l == 2) cbuf[nb * HID + unit] = cc;
    __syncthreads();

    // ---- projection: mean / log_var ----
    if (tid < NB * 2 * LDIM) {
        const int  nn = tid >> 5;
        const int  o  = tid & 31;
        const bool is_mean = (o < LDIM);
        const int  jo = o & (LDIM - 1);
        const float* W  = is_mean ? Wm : Wlv;
        float acc = is_mean ? bm[jo] : blv[jo];
#pragma unroll
        for (int k = 0; k < HID; ++k) acc = fmaf(W[jo * HID + k], cbuf[nn * HID + k], acc);
        out[(is_mean ? 0 : (size_t)BATCH * LDIM) + (size_t)(b0 + nn) * LDIM + jo] = acc;
    }
}

extern "C" void kernel_launch(void* const* d_in, const int* in_sizes, int n_in,
                              void* d_out, int out_size, void* d_ws, size_t ws_size,
                              hipStream_t stream) {
    const float* x    = (const float*)d_in[0];
    const float* Wih0 = (const float*)d_in[1];
    const float* Whh0 = (const float*)d_in[2];
    const float* bih0 = (const float*)d_in[3];
    const float* bhh0 = (const float*)d_in[4];
    const float* Wih1 = (const float*)d_in[5];
    const float* Whh1 = (const float*)d_in[6];
    const float* bih1 = (const float*)d_in[7];
    const float* bhh1 = (const float*)d_in[8];
    const float* Wih2 = (const float*)d_in[9];
    const float* Whh2 = (const float*)d_in[10];
    const float* bih2 = (const float*)d_in[11];
    const float* bhh2 = (const float*)d_in[12];
    const float* Wm   = (const float*)d_in[13];
    const float* bm   = (const float*)d_in[14];
    const float* Wlv  = (const float*)d_in[15];
    const float* blv  = (const float*)d_in[16];
    float* out = (float*)d_out;

    lstm_encoder_kernel<<<dim3(BATCH / NB), dim3(NT), 0, stream>>>(
        x, Wih0, Whh0, bih0, bhh0, Wih1, Whh1, bih1, bhh1,
        Wih2, Whh2, bih2, bhh2, Wm, bm, Wlv, blv, out);
}

// Round 18
// 459.250 us; speedup vs baseline: 1.3189x; 1.0494x over previous
//
#include <hip/hip_runtime.h>

#define T_LEN 1024
#define HID   32
#define LDIM  16
#define BATCH 512
#define NB    4              // batch elems per block (B cols duplicated x4)
#define NT    192            // 3 waves: one per layer (lane-local recurrence)
#define NSLOT 8              // cross-layer ring depth
#define LOG2E 1.44269504f

typedef _Float16 half8  __attribute__((ext_vector_type(8)));
typedef _Float16 half2v __attribute__((ext_vector_type(2)));
typedef float    f32x4  __attribute__((ext_vector_type(4)));
typedef unsigned u32;
typedef unsigned u32x4  __attribute__((ext_vector_type(4)));

#if defined(__has_builtin)
#if __has_builtin(__builtin_amdgcn_rcpf)
#define FAST_RCP(x) __builtin_amdgcn_rcpf(x)
#endif
#if __has_builtin(__builtin_amdgcn_exp2f)
#define FAST_EXP2(x) __builtin_amdgcn_exp2f(x)
#endif
#if __has_builtin(__builtin_amdgcn_cvt_pkrtz)
#define PKRTZ(a, b) __builtin_bit_cast(u32, __builtin_amdgcn_cvt_pkrtz((a), (b)))
#endif
#endif
#ifndef FAST_RCP
#define FAST_RCP(x) (1.0f / (x))
#endif
#ifndef FAST_EXP2
#define FAST_EXP2(x) __expf(0.69314718f * (x))
#endif
#ifndef PKRTZ
static __device__ __forceinline__ u32 pkrtz_fallback(float a, float b) {
    half2v v; v[0] = (_Float16)a; v[1] = (_Float16)b;
    return __builtin_bit_cast(u32, v);
}
#define PKRTZ(a, b) pkrtz_fallback((a), (b))
#endif

#define MFMA(a, b, c) __builtin_amdgcn_mfma_f32_16x16x32_f16((a), (b), (c), 0, 0, 0)

template <int OFF>
__device__ __forceinline__ u32 swzu(u32 v) {
    return (u32)__builtin_amdgcn_ds_swizzle((int)v, OFF);
}

__device__ __forceinline__ void waitc(const u32* p, u32 need) {
    while (__hip_atomic_load(p, __ATOMIC_ACQUIRE, __HIP_MEMORY_SCOPE_WORKGROUP) < need)
        __builtin_amdgcn_s_sleep(1);
}

// static-index select of v[hi]  (rule #20: no dynamic vector indexing)
__device__ __forceinline__ float sel4(f32x4 v, int hi) {
    const float a = (hi & 1) ? v[1] : v[0];
    const float b = (hi & 1) ? v[3] : v[2];
    return (hi & 2) ? b : a;
}

__global__ __launch_bounds__(NT, 1)
void lstm_encoder_kernel(const float* __restrict__ x,
                         const float* __restrict__ Wih0, const float* __restrict__ Whh0,
                         const float* __restrict__ bih0, const float* __restrict__ bhh0,
                         const float* __restrict__ Wih1, const float* __restrict__ Whh1,
                         const float* __restrict__ bih1, const float* __restrict__ bhh1,
                         const float* __restrict__ Wih2, const float* __restrict__ Whh2,
                         const float* __restrict__ bih2, const float* __restrict__ bhh2,
                         const float* __restrict__ Wm,  const float* __restrict__ bm,
                         const float* __restrict__ Wlv, const float* __restrict__ blv,
                         float* __restrict__ out)
{
    const int b0   = blockIdx.x * NB;
    const int tid  = threadIdx.x;
    const int lane = tid & 63;
    const int l    = tid >> 6;        // wave = layer 0..2
    const int n    = lane & 15;       // B/D column; batch = n&3
    const int kc   = lane >> 4;       // k-group / D row-quad
    const int nb   = n & 3;           // batch row
    const int hi   = n >> 2;          // duplicate index: owns units 8kc+hi, 8kc+4+hi

    __shared__ u32 xs[T_LEN * NB];                        // 16 KB packed f16 x [t][nb]
    __shared__ __align__(16) u32x4 ring[3][NSLOT][4][NB]; // 6 KB cross-layer h
    __shared__ u32 cnt[48];                               // 3 counters, 64B apart
    __shared__ float cbuf[NB * HID];

    for (int i = tid; i < NB * T_LEN; i += NT) {
        const int nn = i >> 10, t = i & (T_LEN - 1);
        const float2 v = *(const float2*)(x + ((size_t)(b0 + nn) * T_LEN + t) * 2);
        half2v p; p[0] = (_Float16)v.x; p[1] = (_Float16)v.y;
        xs[t * NB + nn] = __builtin_bit_cast(u32, p);
    }
    if (tid < 48) cnt[tid] = 0u;

    // ---- A fragments + bias (8 tiles, r16-verified layout), exp2-prescaled ----
    // A row m: R = role*32 + 8*(m>>2) + 4*half + (m&3); canonical k: elem 2j+p <-> 8kc+4p+j
    const float* Wih = (l == 0) ? Wih0 : (l == 1) ? Wih1 : Wih2;
    const float* Whh = (l == 0) ? Whh0 : (l == 1) ? Whh1 : Whh2;
    const float* bih = (l == 0) ? bih0 : (l == 1) ? bih1 : bih2;
    const float* bhh = (l == 0) ? bhh0 : (l == 1) ? bhh1 : bhh2;

    half8 aself[8], aprev[8];
    f32x4 biasC[8];
#pragma unroll
    for (int tau = 0; tau < 8; ++tau) {
        const int   role = tau >> 1, hf = tau & 1;
        const float sc   = (role == 2) ? (2.0f * LOG2E) : LOG2E;
        const int   R    = role * 32 + 8 * (n >> 2) + 4 * hf + (n & 3);
#pragma unroll
        for (int j = 0; j < 4; ++j) {
#pragma unroll
            for (int p = 0; p < 2; ++p) {
                const int kidx = 8 * kc + 4 * p + j;
                aself[tau][2 * j + p] = (_Float16)(Whh[R * HID + kidx] * sc);
                aprev[tau][2 * j + p] = (l == 0)
                    ? (_Float16)((kc == 0 && (2 * j + p) < 2) ? Wih[R * 2 + 2 * j + p] * sc : 0.0f)
                    : (_Float16)(Wih[R * HID + kidx] * sc);
            }
        }
#pragma unroll
        for (int r = 0; r < 4; ++r) {
            const int   RD  = role * 32 + 8 * kc + 4 * hf + r;
            const float scD = (role == 2) ? (2.0f * LOG2E) : LOG2E;
            biasC[tau][r] = (bih[RD] + bhh[RD]) * scD;
        }
    }

    u32* cs = &cnt[l * 16];
    u32* cp = &cnt[((l > 0) ? (l - 1) : 0) * 16];
    u32* cn = &cnt[((l < 2) ? (l + 1) : 0) * 16];

    u32x4 hB = {0u, 0u, 0u, 0u};
    float cc0 = 0.0f, cc1 = 0.0f;
    f32x4 accP[8];

    __syncthreads();

// bf0 source for step T at slot S (l0: x-build; else ring read)
#define LOADB(dst, T, S)                                                         \
    do {                                                                         \
        if (l == 0) {                                                            \
            dst[0] = (kc == 0) ? xs[(T) * NB + nb] : 0u;                         \
            dst[1] = 0u; dst[2] = 0u; dst[3] = 0u;                               \
        } else {                                                                 \
            dst = ring[l - 1][(S)][kc][nb];                                      \
        }                                                                        \
    } while (0)

#define PM(dst, bf)                                                              \
    do {                                                                         \
        _Pragma("unroll")                                                        \
        for (int tau = 0; tau < 8; ++tau)                                        \
            dst[tau] = MFMA(aprev[tau], __builtin_bit_cast(half8, bf), biasC[tau]); \
    } while (0)

#define ITER(S)                                                                  \
    do {                                                                         \
        const int t = tb + (S);                                                  \
        if (((S) & 3) == 0) { /* group boundary: amortized waits + on-chain prefetch */ \
            if (l > 0)            waitc(cp, (u32)(t + 4));                       \
            if (l < 2 && t >= 8)  waitc(cn, (u32)(t - 4));                       \
            u32x4 bfb; LOADB(bfb, t, (S));                                       \
            PM(accP, bfb);                                                       \
        }                                                                        \
        f32x4 acc[8];                                                            \
        _Pragma("unroll")                                                        \
        for (int tau = 0; tau < 8; ++tau)  /* THE chain */                       \
            acc[tau] = MFMA(aself[tau], __builtin_bit_cast(half8, hB), accP[tau]); \
        if (((S) & 3) != 3) {  /* off-chain: next step's prev contribution */    \
            u32x4 bfn; LOADB(bfn, t + 1, ((S) + 1) & 7);                         \
            PM(accP, bfn);                                                       \
        }                                                                        \
        const float ai0 = sel4(acc[0], hi), ai1 = sel4(acc[1], hi);              \
        const float af0 = sel4(acc[2], hi), af1 = sel4(acc[3], hi);              \
        const float ag0 = sel4(acc[4], hi), ag1 = sel4(acc[5], hi);              \
        const float ao0 = sel4(acc[6], hi), ao1 = sel4(acc[7], hi);              \
        float h0, h1;                                                            \
        {                                                                        \
            const float ei = FAST_EXP2(-ai0), ef = FAST_EXP2(-af0);              \
            const float eg = FAST_EXP2(-ag0), eo = FAST_EXP2(-ao0);              \
            const float p1  = (1.0f + ei) * (1.0f + eg);                         \
            const float den = p1 * (1.0f + ef);                                  \
            const float tmn = (1.0f - eg) * (1.0f + ef);                         \
            float c_ = fmaf(cc0, p1, tmn) * FAST_RCP(den);                       \
            c_ = fminf(fmaxf(c_, -20.0f), 20.0f);                                \
            cc0 = c_;                                                            \
            const float ec = FAST_EXP2(-2.0f * LOG2E * c_);                      \
            h0 = (1.0f - ec) * FAST_RCP((1.0f + eo) * (1.0f + ec));              \
        }                                                                        \
        {                                                                        \
            const float ei = FAST_EXP2(-ai1), ef = FAST_EXP2(-af1);              \
            const float eg = FAST_EXP2(-ag1), eo = FAST_EXP2(-ao1);              \
            const float p1  = (1.0f + ei) * (1.0f + eg);                         \
            const float den = p1 * (1.0f + ef);                                  \
            const float tmn = (1.0f - eg) * (1.0f + ef);                         \
            float c_ = fmaf(cc1, p1, tmn) * FAST_RCP(den);                       \
            c_ = fminf(fmaxf(c_, -20.0f), 20.0f);                                \
            cc1 = c_;                                                            \
            const float ec = FAST_EXP2(-2.0f * LOG2E * c_);                      \
            h1 = (1.0f - ec) * FAST_RCP((1.0f + eo) * (1.0f + ec));              \
        }                                                                        \
        const u32 q0 = PKRTZ(h0, h1);                                            \
        const u32 q1 = swzu<0x101F>(q0);                                         \
        const u32 q2 = swzu<0x201F>(q0);                                         \
        const u32 q3 = swzu<0x301F>(q0);                                         \
        hB[0] = SELX(0); hB[1] = SELX(1); hB[2] = SELX(2); hB[3] = SELX(3);      \
        if (l < 2 && hi == 0) ring[l][(S)][kc][nb] = hB;                         \
        if (((S) & 3) == 3 && lane == 0)  /* amortized release publish */        \
            __hip_atomic_store(cs, (u32)(t + 1), __ATOMIC_RELEASE,               \
                               __HIP_MEMORY_SCOPE_WORKGROUP);                    \
    } while (0)

#define SELX(j) ((hi == (j)) ? q0 : (hi == ((j) ^ 1)) ? q1 : (hi == ((j) ^ 2)) ? q2 : q3)

    for (int tb = 0; tb < T_LEN; tb += NSLOT) {
        ITER(0); ITER(1); ITER(2); ITER(3);
        ITER(4); ITER(5); ITER(6); ITER(7);
    }
#undef SELX
#undef ITER
#undef PM
#undef LOADB

    if (l == 2) {
        cbuf[nb * HID + 8 * kc + hi]     = cc0;
        cbuf[nb * HID + 8 * kc + 4 + hi] = cc1;
    }
    __syncthreads();

    if (tid < NB * 2 * LDIM) {
        const int  nn = tid >> 5;
        const int  o  = tid & 31;
        const bool is_mean = (o < LDIM);
        const int  jo = o & (LDIM - 1);
        const float* W  = is_mean ? Wm : Wlv;
        float acc = is_mean ? bm[jo] : blv[jo];
#pragma unroll
        for (int k = 0; k < HID; ++k) acc = fmaf(W[jo * HID + k], cbuf[nn * HID + k], acc);
        out[(is_mean ? 0 : (size_t)BATCH * LDIM) + (size_t)(b0 + nn) * LDIM + jo] = acc;
    }
}

extern "C" void kernel_launch(void* const* d_in, const int* in_sizes, int n_in,
                              void* d_out, int out_size, void* d_ws, size_t ws_size,
                              hipStream_t stream) {
    const float* x    = (const float*)d_in[0];
    const float* Wih0 = (const float*)d_in[1];
    const float* Whh0 = (const float*)d_in[2];
    const float* bih0 = (const float*)d_in[3];
    const float* bhh0 = (const float*)d_in[4];
    const float* Wih1 = (const float*)d_in[5];
    const float* Whh1 = (const float*)d_in[6];
    const float* bih1 = (const float*)d_in[7];
    const float* bhh1 = (const float*)d_in[8];
    const float* Wih2 = (const float*)d_in[9];
    const float* Whh2 = (const float*)d_in[10];
    const float* bih2 = (const float*)d_in[11];
    const float* bhh2 = (const float*)d_in[12];
    const float* Wm   = (const float*)d_in[13];
    const float* bm   = (const float*)d_in[14];
    const float* Wlv  = (const float*)d_in[15];
    const float* blv  = (const float*)d_in[16];
    float* out = (float*)d_out;

    lstm_encoder_kernel<<<dim3(BATCH / NB), dim3(NT), 0, stream>>>(
        x, Wih0, Whh0, bih0, bhh0, Wih1, Whh1, bih1, bhh1,
        Wih2, Whh2, bih2, bhh2, Wm, bm, Wlv, blv, out);
}

// Round 19
// 436.844 us; speedup vs baseline: 1.3865x; 1.0513x over previous
//
#include <hip/hip_runtime.h>

#define T_LEN 1024
#define HID   32
#define LDIM  16
#define BATCH 512
#define NB    4              // batch elems per block (B cols duplicated x4, DPP-quad grouped)
#define NT    192            // 3 waves: one per layer (lane-local recurrence)
#define NSLOT 8              // cross-layer ring depth
#define LOG2E 1.44269504f

typedef _Float16 half8  __attribute__((ext_vector_type(8)));
typedef _Float16 half2v __attribute__((ext_vector_type(2)));
typedef float    f32x4  __attribute__((ext_vector_type(4)));
typedef unsigned u32;
typedef unsigned u32x4  __attribute__((ext_vector_type(4)));

#if defined(__has_builtin)
#if __has_builtin(__builtin_amdgcn_rcpf)
#define FAST_RCP(x) __builtin_amdgcn_rcpf(x)
#endif
#if __has_builtin(__builtin_amdgcn_exp2f)
#define FAST_EXP2(x) __builtin_amdgcn_exp2f(x)
#endif
#if __has_builtin(__builtin_amdgcn_cvt_pkrtz)
#define PKRTZ(a, b) __builtin_bit_cast(u32, __builtin_amdgcn_cvt_pkrtz((a), (b)))
#endif
#if __has_builtin(__builtin_amdgcn_mov_dpp)
#define QPERM(v, ctrl) ((u32)__builtin_amdgcn_mov_dpp((int)(v), (ctrl), 0xF, 0xF, true))
#define HAVE_DPP 1
#endif
#endif
#ifndef FAST_RCP
#define FAST_RCP(x) (1.0f / (x))
#endif
#ifndef FAST_EXP2
#define FAST_EXP2(x) __expf(0.69314718f * (x))
#endif
#ifndef PKRTZ
static __device__ __forceinline__ u32 pkrtz_fallback(float a, float b) {
    half2v v; v[0] = (_Float16)a; v[1] = (_Float16)b;
    return __builtin_bit_cast(u32, v);
}
#define PKRTZ(a, b) pkrtz_fallback((a), (b))
#endif

#define MFMA(a, b, c) __builtin_amdgcn_mfma_f32_16x16x32_f16((a), (b), (c), 0, 0, 0)

template <int OFF>
__device__ __forceinline__ u32 swzu(u32 v) {
    return (u32)__builtin_amdgcn_ds_swizzle((int)v, OFF);
}

__device__ __forceinline__ void waitc(const u32* p, u32 need) {
    while (__hip_atomic_load(p, __ATOMIC_ACQUIRE, __HIP_MEMORY_SCOPE_WORKGROUP) < need)
        __builtin_amdgcn_s_sleep(1);
}

// static-index select of v[hi]  (rule #20: no dynamic vector indexing)
__device__ __forceinline__ float sel4(f32x4 v, int hi) {
    const float a = (hi & 1) ? v[1] : v[0];
    const float b = (hi & 1) ? v[3] : v[2];
    return (hi & 2) ? b : a;
}

__global__ __launch_bounds__(NT, 1)
void lstm_encoder_kernel(const float* __restrict__ x,
                         const float* __restrict__ Wih0, const float* __restrict__ Whh0,
                         const float* __restrict__ bih0, const float* __restrict__ bhh0,
                         const float* __restrict__ Wih1, const float* __restrict__ Whh1,
                         const float* __restrict__ bih1, const float* __restrict__ bhh1,
                         const float* __restrict__ Wih2, const float* __restrict__ Whh2,
                         const float* __restrict__ bih2, const float* __restrict__ bhh2,
                         const float* __restrict__ Wm,  const float* __restrict__ bm,
                         const float* __restrict__ Wlv, const float* __restrict__ blv,
                         float* __restrict__ out)
{
    const int b0   = blockIdx.x * NB;
    const int tid  = threadIdx.x;
    const int lane = tid & 63;
    const int l    = tid >> 6;        // wave = layer 0..2
    const int n    = lane & 15;       // B/D column
    const int kc   = lane >> 4;       // k-group / D row-quad
    const int nb   = n >> 2;          // batch row (quad-contiguous: lanes 4nb..4nb+3)
    const int hi   = n & 3;           // duplicate index within DPP quad

    __shared__ u32 xs[T_LEN * NB];                        // 16 KB packed f16 x [t][nb]
    __shared__ __align__(16) u32x4 ring[3][NSLOT][4][NB]; // 6 KB cross-layer h
    __shared__ u32 cnt[48];                               // 3 counters, 64B apart
    __shared__ float cbuf[NB * HID];

    for (int i = tid; i < NB * T_LEN; i += NT) {
        const int nn = i >> 10, t = i & (T_LEN - 1);
        const float2 v = *(const float2*)(x + ((size_t)(b0 + nn) * T_LEN + t) * 2);
        half2v p; p[0] = (_Float16)v.x; p[1] = (_Float16)v.y;
        xs[t * NB + nn] = __builtin_bit_cast(u32, p);
    }
    if (tid < 48) cnt[tid] = 0u;

    // ---- A fragments + bias (8 tiles, r16-verified layout), exp2-prescaled ----
    // A row m: R = role*32 + 8*(m>>2) + 4*half + (m&3); canonical k: elem 2j+p <-> 8kc+4p+j
    const float* Wih = (l == 0) ? Wih0 : (l == 1) ? Wih1 : Wih2;
    const float* Whh = (l == 0) ? Whh0 : (l == 1) ? Whh1 : Whh2;
    const float* bih = (l == 0) ? bih0 : (l == 1) ? bih1 : bih2;
    const float* bhh = (l == 0) ? bhh0 : (l == 1) ? bhh1 : bhh2;

    half8 aself[8], aprev[8];
    f32x4 biasC[8];
#pragma unroll
    for (int tau = 0; tau < 8; ++tau) {
        const int   role = tau >> 1, hf = tau & 1;
        const float sc   = (role == 2) ? (2.0f * LOG2E) : LOG2E;
        const int   R    = role * 32 + 8 * (n >> 2) + 4 * hf + (n & 3);
#pragma unroll
        for (int j = 0; j < 4; ++j) {
#pragma unroll
            for (int p = 0; p < 2; ++p) {
                const int kidx = 8 * kc + 4 * p + j;
                aself[tau][2 * j + p] = (_Float16)(Whh[R * HID + kidx] * sc);
                aprev[tau][2 * j + p] = (l == 0)
                    ? (_Float16)((kc == 0 && (2 * j + p) < 2) ? Wih[R * 2 + 2 * j + p] * sc : 0.0f)
                    : (_Float16)(Wih[R * HID + kidx] * sc);
            }
        }
#pragma unroll
        for (int r = 0; r < 4; ++r) {
            const int   RD  = role * 32 + 8 * kc + 4 * hf + r;
            const float scD = (role == 2) ? (2.0f * LOG2E) : LOG2E;
            biasC[tau][r] = (bih[RD] + bhh[RD]) * scD;
        }
    }

    u32* cs = &cnt[l * 16];
    u32* cp = &cnt[((l > 0) ? (l - 1) : 0) * 16];
    u32* cn = &cnt[((l < 2) ? (l + 1) : 0) * 16];

    u32x4 hB = {0u, 0u, 0u, 0u};
    float cc0 = 0.0f, cc1 = 0.0f;
    f32x4 accP[8];

    __syncthreads();

// bf0 source for step T at slot S (l0: x-build; else ring read)
#define LOADB(dst, T, S)                                                         \
    do {                                                                         \
        if (l == 0) {                                                            \
            dst[0] = (kc == 0) ? xs[(T) * NB + nb] : 0u;                         \
            dst[1] = 0u; dst[2] = 0u; dst[3] = 0u;                               \
        } else {                                                                 \
            dst = ring[l - 1][(S)][kc][nb];                                      \
        }                                                                        \
    } while (0)

#define PM(dst, bf)                                                              \
    do {                                                                         \
        _Pragma("unroll")                                                        \
        for (int tau = 0; tau < 8; ++tau)                                        \
            dst[tau] = MFMA(aprev[tau], __builtin_bit_cast(half8, bf), biasC[tau]); \
    } while (0)

#ifdef HAVE_DPP
#define QX1(v) QPERM(v, 0xB1)   /* quad_perm [1,0,3,2] = hi^1 */
#define QX2(v) QPERM(v, 0x4E)   /* quad_perm [2,3,0,1] = hi^2 */
#define QX3(v) QPERM(v, 0x1B)   /* quad_perm [3,2,1,0] = hi^3 */
#else
#define QX1(v) swzu<0x041F>(v)  /* xor-1 within quad */
#define QX2(v) swzu<0x081F>(v)  /* xor-2 */
#define QX3(v) swzu<0x0C1F>(v)  /* xor-3 */
#endif

#define ITER(S)                                                                  \
    do {                                                                         \
        const int t = tb + (S);                                                  \
        if (((S) & 3) == 0) { /* group boundary: amortized waits + on-chain prefetch */ \
            if (l > 0)            waitc(cp, (u32)(t + 4));                       \
            if (l < 2 && t >= 8)  waitc(cn, (u32)(t - 4));                       \
            u32x4 bfb; LOADB(bfb, t, (S));                                       \
            PM(accP, bfb);                                                       \
        }                                                                        \
        f32x4 acc[8];                                                            \
        _Pragma("unroll")                                                        \
        for (int tau = 0; tau < 8; ++tau)  /* THE chain */                       \
            acc[tau] = MFMA(aself[tau], __builtin_bit_cast(half8, hB), accP[tau]); \
        if (((S) & 3) != 3) {  /* off-chain: next step's prev contribution */    \
            u32x4 bfn; LOADB(bfn, t + 1, ((S) + 1) & 7);                         \
            PM(accP, bfn);                                                       \
        }                                                                        \
        const float ai0 = sel4(acc[0], hi), ai1 = sel4(acc[1], hi);              \
        const float af0 = sel4(acc[2], hi), af1 = sel4(acc[3], hi);              \
        const float ag0 = sel4(acc[4], hi), ag1 = sel4(acc[5], hi);              \
        const float ao0 = sel4(acc[6], hi), ao1 = sel4(acc[7], hi);              \
        float h0, h1;                                                            \
        {                                                                        \
            const float ei = FAST_EXP2(-ai0), ef = FAST_EXP2(-af0);              \
            const float eg = FAST_EXP2(-ag0), eo = FAST_EXP2(-ao0);              \
            const float p1  = (1.0f + ei) * (1.0f + eg);                         \
            const float den = p1 * (1.0f + ef);                                  \
            const float tmn = (1.0f - eg) * (1.0f + ef);                         \
            float c_ = fmaf(cc0, p1, tmn) * FAST_RCP(den);                       \
            c_ = fminf(fmaxf(c_, -20.0f), 20.0f);                                \
            cc0 = c_;                                                            \
            const float ec = FAST_EXP2(-2.0f * LOG2E * c_);                      \
            h0 = (1.0f - ec) * FAST_RCP((1.0f + eo) * (1.0f + ec));              \
        }                                                                        \
        {                                                                        \
            const float ei = FAST_EXP2(-ai1), ef = FAST_EXP2(-af1);              \
            const float eg = FAST_EXP2(-ag1), eo = FAST_EXP2(-ao1);              \
            const float p1  = (1.0f + ei) * (1.0f + eg);                         \
            const float den = p1 * (1.0f + ef);                                  \
            const float tmn = (1.0f - eg) * (1.0f + ef);                         \
            float c_ = fmaf(cc1, p1, tmn) * FAST_RCP(den);                       \
            c_ = fminf(fmaxf(c_, -20.0f), 20.0f);                                \
            cc1 = c_;                                                            \
            const float ec = FAST_EXP2(-2.0f * LOG2E * c_);                      \
            h1 = (1.0f - ec) * FAST_RCP((1.0f + eo) * (1.0f + ec));              \
        }                                                                        \
        const u32 q0 = PKRTZ(h0, h1);                                            \
        const u32 q1 = QX1(q0);                                                  \
        const u32 q2 = QX2(q0);                                                  \
        const u32 q3 = QX3(q0);                                                  \
        hB[0] = SELX(0); hB[1] = SELX(1); hB[2] = SELX(2); hB[3] = SELX(3);      \
        if (l < 2 && hi == 0) ring[l][(S)][kc][nb] = hB;                         \
        if (((S) & 3) == 3 && lane == 0)  /* amortized release publish */        \
            __hip_atomic_store(cs, (u32)(t + 1), __ATOMIC_RELEASE,               \
                               __HIP_MEMORY_SCOPE_WORKGROUP);                    \
    } while (0)

#define SELX(j) ((hi == (j)) ? q0 : (hi == ((j) ^ 1)) ? q1 : (hi == ((j) ^ 2)) ? q2 : q3)

    for (int tb = 0; tb < T_LEN; tb += NSLOT) {
        ITER(0); ITER(1); ITER(2); ITER(3);
        ITER(4); ITER(5); ITER(6); ITER(7);
    }
#undef SELX
#undef ITER
#undef PM
#undef LOADB
#undef QX1
#undef QX2
#undef QX3

    if (l == 2) {
        cbuf[nb * HID + 8 * kc + hi]     = cc0;
        cbuf[nb * HID + 8 * kc + 4 + hi] = cc1;
    }
    __syncthreads();

    if (tid < NB * 2 * LDIM) {
        const int  nn = tid >> 5;
        const int  o  = tid & 31;
        const bool is_mean = (o < LDIM);
        const int  jo = o & (LDIM - 1);
        const float* W  = is_mean ? Wm : Wlv;
        float acc = is_mean ? bm[jo] : blv[jo];
#pragma unroll
        for (int k = 0; k < HID; ++k) acc = fmaf(W[jo * HID + k], cbuf[nn * HID + k], acc);
        out[(is_mean ? 0 : (size_t)BATCH * LDIM) + (size_t)(b0 + nn) * LDIM + jo] = acc;
    }
}

extern "C" void kernel_launch(void* const* d_in, const int* in_sizes, int n_in,
                              void* d_out, int out_size, void* d_ws, size_t ws_size,
                              hipStream_t stream) {
    const float* x    = (const float*)d_in[0];
    const float* Wih0 = (const float*)d_in[1];
    const float* Whh0 = (const float*)d_in[2];
    const float* bih0 = (const float*)d_in[3];
    const float* bhh0 = (const float*)d_in[4];
    const float* Wih1 = (const float*)d_in[5];
    const float* Whh1 = (const float*)d_in[6];
    const float* bih1 = (const float*)d_in[7];
    const float* bhh1 = (const float*)d_in[8];
    const float* Wih2 = (const float*)d_in[9];
    const float* Whh2 = (const float*)d_in[10];
    const float* bih2 = (const float*)d_in[11];
    const float* bhh2 = (const float*)d_in[12];
    const float* Wm   = (const float*)d_in[13];
    const float* bm   = (const float*)d_in[14];
    const float* Wlv  = (const float*)d_in[15];
    const float* blv  = (const float*)d_in[16];
    float* out = (float*)d_out;

    lstm_encoder_kernel<<<dim3(BATCH / NB), dim3(NT), 0, stream>>>(
        x, Wih0, Whh0, bih0, bhh0, Wih1, Whh1, bih1, bhh1,
        Wih2, Whh2, bih2, bhh2, Wm, bm, Wlv, blv, out);
}